// Round 4
// baseline (254.049 us; speedup 1.0000x reference)
//
#include <hip/hip_runtime.h>
#include <cmath>

#define HH 256
#define WW 256
#define RAD 12
#define KLEN 25
#define NMAPS 512
#define ESTRIP 32
#define NSTRIP (HH / ESTRIP)     // 8
#define NITER (ESTRIP + 2)       // 34

// ---------------------------------------------------------------------------
// Kernel A: 256-thread blocks = 4 INDEPENDENT strip-waves (same map).
// Each wave: 64 lanes x 4 cols; 25-deep float4 register ring for vertical
// conv; horizontal conv via 7 aligned ds_read_b128 from its private vrow
// slice. No __syncthreads (waves share nothing). Rolled loop (I$-resident),
// next-row software prefetch.
// ---------------------------------------------------------------------------
__global__ __launch_bounds__(256, 3) void blur_peak_strip(
    const float* __restrict__ in,
    float* __restrict__ sval,
    int* __restrict__ sidx,
    int* __restrict__ scnt)
{
    __shared__ __align__(16) float vrow[4][WW + 2 * RAD];   // per-wave slice

    const int tid  = threadIdx.x;
    const int l    = tid & 63;          // lane, owns cols 4l..4l+3
    const int wv   = tid >> 6;          // wave id in block
    const int sid  = blockIdx.x * 4 + wv;   // strip id 0..4095
    const int m    = sid >> 3;
    const int strip = sid & 7;
    const float4* map4 = reinterpret_cast<const float4*>(in) + (size_t)m * (HH * WW / 4);

    const int e0 = strip * ESTRIP;
    const int o0 = e0 - 1;

    // Full 25-tap coefficients (expf of literals -> compile-time folded).
    float kf[KLEN];
    {
        float s = 0.f;
        float h[RAD + 1];
#pragma unroll
        for (int i = 0; i <= RAD; ++i) {
            float tt = (float)(i - RAD);
            h[i] = expf(-(tt * tt) / 18.0f);
            s += (i < RAD) ? 2.f * h[i] : h[i];
        }
#pragma unroll
        for (int i = 0; i <= RAD; ++i) h[i] /= s;
#pragma unroll
        for (int i = 0; i < KLEN; ++i) kf[i] = h[(i <= RAD) ? i : (2 * RAD - i)];
    }

    // Register ring: after append in iter t (o=o0+t), r*[i] = padded[o+i],
    // padded[q] = raw[mirr(q-12)].
    float rx[KLEN], ry[KLEN], rz[KLEN], rw[KLEN];
#pragma unroll
    for (int i = 1; i < KLEN; ++i) {
        int q = o0 + i - 1 - RAD;
        int r = (q < 0) ? (-q - 1) : q;      // top mirror (bottom impossible here)
        float4 t4 = map4[(size_t)r * (WW / 4) + l];
        rx[i] = t4.x; ry[i] = t4.y; rz[i] = t4.z; rw[i] = t4.w;
    }
    rx[0] = ry[0] = rz[0] = rw[0] = 0.f;

    // prefetch the row appended at t=0: raw row o0+RAD (always in [11,235])
    float4 pf = map4[(size_t)(o0 + RAD) * (WW / 4) + l];

    float4 g0v  = make_float4(0.f, 0.f, 0.f, 0.f);
    float4 gm1v = g0v, gm2v = g0v;

    float bval = -1.f;
    int   bidx = 0x7FFFFFFF;
    int   cnt  = 0;

    float* vr = vrow[wv];

#pragma unroll 4
    for (int t = 0; t < NITER; ++t) {
        const int o = o0 + t;

        // ---- append prefetched row; shift ring ----
#pragma unroll
        for (int i = 0; i < KLEN - 1; ++i) {
            rx[i] = rx[i + 1]; ry[i] = ry[i + 1];
            rz[i] = rz[i + 1]; rw[i] = rw[i + 1];
        }
        rx[KLEN - 1] = pf.x; ry[KLEN - 1] = pf.y;
        rz[KLEN - 1] = pf.z; rw[KLEN - 1] = pf.w;

        // ---- issue prefetch for t+1 (bottom mirror) ----
        {
            int rr = o + 1 + RAD;
            int r = (rr > HH - 1) ? (2 * HH - 1 - rr) : rr;
            pf = map4[(size_t)r * (WW / 4) + l];
        }

        // ---- vertical conv: 25 direct taps ----
        float vx = 0.f, vy = 0.f, vz = 0.f, vw = 0.f;
#pragma unroll
        for (int d = 0; d < KLEN; ++d) {
            vx += kf[d] * rx[d]; vy += kf[d] * ry[d];
            vz += kf[d] * rz[d]; vw += kf[d] * rw[d];
        }

        // ---- write padded v row (own wave's slice; no cross-wave sharing) ----
        reinterpret_cast<float4*>(vr + RAD)[l] = make_float4(vx, vy, vz, vw);
        if (l < 3)   reinterpret_cast<float4*>(vr)[2 - l]   = make_float4(vw, vz, vy, vx);
        if (l >= 61) reinterpret_cast<float4*>(vr)[130 - l] = make_float4(vw, vz, vy, vx);
        __builtin_amdgcn_wave_barrier();   // compiler fence: keep writes before reads

        // ---- horizontal conv: 7 aligned b128 reads, eager accumulate ----
        float acc0 = 0.f, acc1 = 0.f, acc2 = 0.f, acc3 = 0.f;
#pragma unroll
        for (int k = 0; k < 7; ++k) {
            float4 t4 = reinterpret_cast<const float4*>(vr)[l + k];
#pragma unroll
            for (int e = 0; e < 4; ++e) {
                const int i = 4 * k + e;
                const float wval = (e == 0) ? t4.x : (e == 1) ? t4.y : (e == 2) ? t4.z : t4.w;
                if (i <= 24)           acc0 += kf[i]     * wval;
                if (i >= 1 && i <= 25) acc1 += kf[i - 1] * wval;
                if (i >= 2 && i <= 26) acc2 += kf[i - 2] * wval;
                if (i >= 3)            acc3 += kf[i - 3] * wval;
            }
        }
        gm2v = gm1v; gm1v = g0v;
        g0v = make_float4(acc0, acc1, acc2, acc3);

        // ---- peak eval at row e = o-1 ----
        if (t >= 2) {
            const int e = o - 1;
            float lf0 = __shfl_up(gm1v.w, 1);   if (l == 0)  lf0 = 0.f;
            float rt3 = __shfl_down(gm1v.x, 1); if (l == 63) rt3 = 0.f;
            const bool etop = (e == 0), ebot = (e == HH - 1);
            const float gm1a[4] = {gm1v.x, gm1v.y, gm1v.z, gm1v.w};
            const float gm2a[4] = {gm2v.x, gm2v.y, gm2v.z, gm2v.w};
            const float g0a[4]  = {g0v.x,  g0v.y,  g0v.z,  g0v.w};
            const float mva[4]  = {rx[11], ry[11], rz[11], rw[11]};  // raw row e
#pragma unroll
            for (int q = 0; q < 4; ++q) {
                float gE = gm1a[q];
                float up = etop ? 0.f : gm2a[q];
                float dn = ebot ? 0.f : g0a[q];
                float lf = (q == 0) ? lf0 : gm1a[q - 1];
                float rt = (q == 3) ? rt3 : gm1a[q + 1];
                float mx = fmaxf(fmaxf(up, dn), fmaxf(lf, rt));
                bool pk = (gE >= mx) && (gE > 0.01f);
                if (pk) {
                    cnt++;
                    float mv = mva[q];
                    int fi = e * WW + 4 * l + q;
                    if (mv > bval) { bval = mv; bidx = fi; }   // strict > keeps first
                }
            }
        }
    }

    // ---- 64-lane butterfly: (max val, min idx on tie), sum count ----
#pragma unroll
    for (int off = 32; off > 0; off >>= 1) {
        float v2 = __shfl_xor(bval, off);
        int   i2 = __shfl_xor(bidx, off);
        int   c2 = __shfl_xor(cnt,  off);
        if (v2 > bval || (v2 == bval && i2 < bidx)) { bval = v2; bidx = i2; }
        cnt += c2;
    }
    if (l == 0) { sval[sid] = bval; sidx[sid] = bidx; scnt[sid] = cnt; }
}

// ---------------------------------------------------------------------------
// Kernel B: per-map combine strips + 5x5 window sums at winner + output logic
// ---------------------------------------------------------------------------
__global__ __launch_bounds__(256) void finalize_kernel(
    const float* __restrict__ in,
    const float* __restrict__ sval,
    const int* __restrict__ sidx,
    const int* __restrict__ scnt,
    float* __restrict__ out)
{
    int t = blockIdx.x * blockDim.x + threadIdx.x;
    if (t >= NMAPS) return;

    float BV = -1.f; int BI = 0x7FFFFFFF; int C = 0;
#pragma unroll
    for (int s2 = 0; s2 < NSTRIP; ++s2) {
        int k = t * NSTRIP + s2;
        float v = sval[k]; int i = sidx[k];
        if (v > BV || (v == BV && i < BI)) { BV = v; BI = i; }
        C += scnt[k];
    }

    bool valid = (C == 1) || ((C > 1) && (BV >= 0.8f));

    float kx = -999.999f, ky = -999.999f, conf = 0.f;
    if (valid) {
        int pr = BI / WW, pc = BI % WW;
        const float* map = in + (size_t)t * HH * WW;
        float S = 0.f, SX = 0.f, SY = 0.f;
#pragma unroll
        for (int dr = -2; dr <= 2; ++dr) {
            int r = pr + dr;
            if (r < 0 || r >= HH) continue;
#pragma unroll
            for (int dc = -2; dc <= 2; ++dc) {
                int cc = pc + dc;
                if (cc < 0 || cc >= WW) continue;
                float mv = map[r * WW + cc];
                S  += mv;
                SX += mv * (float)cc;
                SY += mv * (float)r;
            }
        }
        float x = (S == 0.f) ? (float)pc : (SX / S);
        float y = (S == 0.f) ? (float)pr : (SY / S);
        kx = x + 0.4395f;
        ky = y + 0.4395f;
        conf = 1.f;
    }
    out[t * 3 + 0] = kx;
    out[t * 3 + 1] = ky;
    out[t * 3 + 2] = conf;
}

extern "C" void kernel_launch(void* const* d_in, const int* in_sizes, int n_in,
                              void* d_out, int out_size, void* d_ws, size_t ws_size,
                              hipStream_t stream) {
    const float* in = (const float*)d_in[0];
    float* out = (float*)d_out;

    const int nstrips = NMAPS * NSTRIP;   // 4096
    float* sval = (float*)d_ws;
    int*   sidx = (int*)((char*)d_ws + (size_t)nstrips * 4);
    int*   scnt = (int*)((char*)d_ws + (size_t)nstrips * 8);

    blur_peak_strip<<<nstrips / 4, 256, 0, stream>>>(in, sval, sidx, scnt);
    finalize_kernel<<<(NMAPS + 255) / 256, 256, 0, stream>>>(in, sval, sidx, scnt, out);
}

// Round 5
// 96.897 us; speedup vs baseline: 2.6219x; 2.6219x over previous
//
#include <hip/hip_runtime.h>
#include <cmath>

#define HH 256
#define WW 256
#define RAD 12
#define KLEN 25
#define NMAPS 512
#define ESTRIP 32
#define NSTRIP (HH / ESTRIP)   // 8
#define RING 29                // 24 carried + 5 fresh slots per macro-iter

// ---------------------------------------------------------------------------
// Kernel A: 256-thread blocks = 4 INDEPENDENT strip-waves. Each wave: 64
// lanes x 4 cols. Vertical conv from a 29-slot float4 register ring with
// fully static indices (5-row macro-iterations, rotate-by-5 at macro end).
// Horizontal conv via 7 aligned ds_read_b128 from a per-wave padded LDS row.
// No __syncthreads. 5-row prefetch issued one full macro-iteration ahead.
// ---------------------------------------------------------------------------
__global__ __launch_bounds__(256, 2) void blur_peak_strip(
    const float* __restrict__ in,
    float* __restrict__ sval,
    int* __restrict__ sidx,
    int* __restrict__ scnt)
{
    __shared__ __align__(16) float vrow[4][WW + 2 * RAD];   // per-wave slice

    const int tid  = threadIdx.x;
    const int l    = tid & 63;           // lane, owns cols 4l..4l+3
    const int wv   = tid >> 6;
    const int sid  = blockIdx.x * 4 + wv;    // strip id 0..4095
    const int m    = sid >> 3;
    const int strip = sid & 7;
    const float4* map4 = reinterpret_cast<const float4*>(in) + (size_t)m * (HH * WW / 4);

    const int e0 = strip * ESTRIP;
    const int o0 = e0 - 1;

    // Gaussian taps (identical float32 math to R2-R4; folds at compile time).
    float kf[KLEN];
    {
        float s = 0.f; float h[RAD + 1];
#pragma unroll
        for (int i = 0; i <= RAD; ++i) {
            float tt = (float)(i - RAD);
            h[i] = expf(-(tt * tt) / 18.0f);
            s += (i < RAD) ? 2.f * h[i] : h[i];
        }
#pragma unroll
        for (int i = 0; i <= RAD; ++i) h[i] /= s;
#pragma unroll
        for (int i = 0; i < KLEN; ++i) kf[i] = h[(i <= RAD) ? i : (2 * RAD - i)];
    }

    // Ring: slot i holds padded[oT + i], oT = o0 + 5*T; padded[q] = raw[mirr(q-12)]
    float rxx[RING], ryy[RING], rzz[RING], rww[RING];
#pragma unroll
    for (int i = 0; i < RING; ++i) {
        int q = o0 + i - RAD;
        int r = (q < 0) ? (-q - 1) : q;    // top mirror only (bottom impossible here)
        float4 t4 = map4[(size_t)r * (WW / 4) + l];
        rxx[i] = t4.x; ryy[i] = t4.y; rzz[i] = t4.z; rww[i] = t4.w;
    }

    float4 g0v  = make_float4(0.f, 0.f, 0.f, 0.f);
    float4 gm1v = g0v, gm2v = g0v;
    float bval = -1.f;
    int   bidx = 0x7FFFFFFF;
    int   cnt  = 0;
    float* vr = vrow[wv];
    float4 pf0, pf1, pf2, pf3, pf4;

// issue next macro-iter's 5 row loads; consumed by ROTATE at macro end.
// raw row of first prefetch: (oT + 29) - 12 = o0 + 5T + 17  (never < 0)
#define PREFETCH(TT)                                                          \
    {                                                                         \
        int rb = o0 + 5 * (TT) + 17;                                          \
        int r0 = rb, r1 = rb + 1, r2 = rb + 2, r3 = rb + 3, r4 = rb + 4;      \
        if (r0 > HH - 1) r0 = 2 * HH - 1 - r0;                                \
        if (r1 > HH - 1) r1 = 2 * HH - 1 - r1;                                \
        if (r2 > HH - 1) r2 = 2 * HH - 1 - r2;                                \
        if (r3 > HH - 1) r3 = 2 * HH - 1 - r3;                                \
        if (r4 > HH - 1) r4 = 2 * HH - 1 - r4;                                \
        pf0 = map4[(size_t)r0 * (WW / 4) + l];                                \
        pf1 = map4[(size_t)r1 * (WW / 4) + l];                                \
        pf2 = map4[(size_t)r2 * (WW / 4) + l];                                \
        pf3 = map4[(size_t)r3 * (WW / 4) + l];                                \
        pf4 = map4[(size_t)r4 * (WW / 4) + l];                                \
    }

#define ROTATE()                                                              \
    {                                                                         \
        _Pragma("unroll")                                                     \
        for (int i = 0; i < RING - 5; ++i) {                                  \
            rxx[i] = rxx[i + 5]; ryy[i] = ryy[i + 5];                         \
            rzz[i] = rzz[i + 5]; rww[i] = rww[i + 5];                         \
        }                                                                     \
        rxx[24] = pf0.x; ryy[24] = pf0.y; rzz[24] = pf0.z; rww[24] = pf0.w;   \
        rxx[25] = pf1.x; ryy[25] = pf1.y; rzz[25] = pf1.z; rww[25] = pf1.w;   \
        rxx[26] = pf2.x; ryy[26] = pf2.y; rzz[26] = pf2.z; rww[26] = pf2.w;   \
        rxx[27] = pf3.x; ryy[27] = pf3.y; rzz[27] = pf3.z; rww[27] = pf3.w;   \
        rxx[28] = pf4.x; ryy[28] = pf4.y; rzz[28] = pf4.z; rww[28] = pf4.w;   \
    }

// one output row: g row o = oT + PP; all ring indices compile-time constants
#define ROW(TT, PP)                                                           \
    {                                                                         \
        float vx = 0.f, vy = 0.f, vz = 0.f, vw = 0.f;                         \
        _Pragma("unroll")                                                     \
        for (int d = 0; d < KLEN; ++d) {                                      \
            vx += kf[d] * rxx[(PP) + d]; vy += kf[d] * ryy[(PP) + d];         \
            vz += kf[d] * rzz[(PP) + d]; vw += kf[d] * rww[(PP) + d];         \
        }                                                                     \
        reinterpret_cast<float4*>(vr + RAD)[l] = make_float4(vx, vy, vz, vw); \
        if (l < 3)   reinterpret_cast<float4*>(vr)[2 - l]   = make_float4(vw, vz, vy, vx); \
        if (l >= 61) reinterpret_cast<float4*>(vr)[130 - l] = make_float4(vw, vz, vy, vx); \
        __builtin_amdgcn_wave_barrier();                                      \
        float acc0 = 0.f, acc1 = 0.f, acc2 = 0.f, acc3 = 0.f;                 \
        _Pragma("unroll")                                                     \
        for (int k = 0; k < 7; ++k) {                                         \
            float4 t4 = reinterpret_cast<const float4*>(vr)[l + k];           \
            _Pragma("unroll")                                                 \
            for (int e = 0; e < 4; ++e) {                                     \
                const int i = 4 * k + e;                                      \
                const float wval = (e==0)?t4.x:(e==1)?t4.y:(e==2)?t4.z:t4.w;  \
                if (i <= 24)           acc0 += kf[i]     * wval;              \
                if (i >= 1 && i <= 25) acc1 += kf[i - 1] * wval;              \
                if (i >= 2 && i <= 26) acc2 += kf[i - 2] * wval;              \
                if (i >= 3)            acc3 += kf[i - 3] * wval;              \
            }                                                                 \
        }                                                                     \
        __builtin_amdgcn_wave_barrier();                                      \
        gm2v = gm1v; gm1v = g0v;                                              \
        g0v = make_float4(acc0, acc1, acc2, acc3);                            \
        if ((TT) > 0 || (PP) >= 2) {                                          \
            const int erow = o0 + 5 * (TT) + (PP) - 1;                        \
            float lf0 = __shfl_up(gm1v.w, 1);   if (l == 0)  lf0 = 0.f;       \
            float rt3 = __shfl_down(gm1v.x, 1); if (l == 63) rt3 = 0.f;       \
            const bool etop = (erow == 0), ebot = (erow == HH - 1);           \
            const float gm1a[4] = {gm1v.x, gm1v.y, gm1v.z, gm1v.w};           \
            const float gm2a[4] = {gm2v.x, gm2v.y, gm2v.z, gm2v.w};           \
            const float g0a[4]  = {g0v.x,  g0v.y,  g0v.z,  g0v.w};            \
            const float mva[4]  = {rxx[(PP) + 11], ryy[(PP) + 11],            \
                                   rzz[(PP) + 11], rww[(PP) + 11]};           \
            _Pragma("unroll")                                                 \
            for (int q = 0; q < 4; ++q) {                                     \
                float gE = gm1a[q];                                           \
                float up = etop ? 0.f : gm2a[q];                              \
                float dn = ebot ? 0.f : g0a[q];                               \
                float lf = (q == 0) ? lf0 : gm1a[q - 1];                      \
                float rt = (q == 3) ? rt3 : gm1a[q + 1];                      \
                float mx = fmaxf(fmaxf(up, dn), fmaxf(lf, rt));               \
                bool pk = (gE >= mx) && (gE > 0.01f);                         \
                if (pk) {                                                     \
                    cnt++;                                                    \
                    float mv = mva[q];                                        \
                    int fi = erow * WW + 4 * l + q;                           \
                    if (mv > bval) { bval = mv; bidx = fi; }                  \
                }                                                             \
            }                                                                 \
        }                                                                     \
    }

#pragma unroll 1
    for (int T = 0; T < 6; ++T) {       // rows t = 5T .. 5T+4  (0..29)
        PREFETCH(T);
        ROW(T, 0); ROW(T, 1); ROW(T, 2); ROW(T, 3); ROW(T, 4);
        ROTATE();
    }
    // tail: rows t = 30..33 (static; ring slots 0..27 valid, no prefetch)
    ROW(6, 0); ROW(6, 1); ROW(6, 2); ROW(6, 3);

#undef ROW
#undef ROTATE
#undef PREFETCH

    // ---- 64-lane butterfly: (max val, min idx on tie), sum count ----
#pragma unroll
    for (int off = 32; off > 0; off >>= 1) {
        float v2 = __shfl_xor(bval, off);
        int   i2 = __shfl_xor(bidx, off);
        int   c2 = __shfl_xor(cnt,  off);
        if (v2 > bval || (v2 == bval && i2 < bidx)) { bval = v2; bidx = i2; }
        cnt += c2;
    }
    if (l == 0) { sval[sid] = bval; sidx[sid] = bidx; scnt[sid] = cnt; }
}

// ---------------------------------------------------------------------------
// Kernel B: per-map combine strips + 5x5 window sums at winner + output logic
// ---------------------------------------------------------------------------
__global__ __launch_bounds__(256) void finalize_kernel(
    const float* __restrict__ in,
    const float* __restrict__ sval,
    const int* __restrict__ sidx,
    const int* __restrict__ scnt,
    float* __restrict__ out)
{
    int t = blockIdx.x * blockDim.x + threadIdx.x;
    if (t >= NMAPS) return;

    float BV = -1.f; int BI = 0x7FFFFFFF; int C = 0;
#pragma unroll
    for (int s2 = 0; s2 < NSTRIP; ++s2) {
        int k = t * NSTRIP + s2;
        float v = sval[k]; int i = sidx[k];
        if (v > BV || (v == BV && i < BI)) { BV = v; BI = i; }
        C += scnt[k];
    }

    bool valid = (C == 1) || ((C > 1) && (BV >= 0.8f));

    float kx = -999.999f, ky = -999.999f, conf = 0.f;
    if (valid) {
        int pr = BI / WW, pc = BI % WW;
        const float* map = in + (size_t)t * HH * WW;
        float S = 0.f, SX = 0.f, SY = 0.f;
#pragma unroll
        for (int dr = -2; dr <= 2; ++dr) {
            int r = pr + dr;
            if (r < 0 || r >= HH) continue;
#pragma unroll
            for (int dc = -2; dc <= 2; ++dc) {
                int cc = pc + dc;
                if (cc < 0 || cc >= WW) continue;
                float mv = map[r * WW + cc];
                S  += mv;
                SX += mv * (float)cc;
                SY += mv * (float)r;
            }
        }
        float x = (S == 0.f) ? (float)pc : (SX / S);
        float y = (S == 0.f) ? (float)pr : (SY / S);
        kx = x + 0.4395f;
        ky = y + 0.4395f;
        conf = 1.f;
    }
    out[t * 3 + 0] = kx;
    out[t * 3 + 1] = ky;
    out[t * 3 + 2] = conf;
}

extern "C" void kernel_launch(void* const* d_in, const int* in_sizes, int n_in,
                              void* d_out, int out_size, void* d_ws, size_t ws_size,
                              hipStream_t stream) {
    const float* in = (const float*)d_in[0];
    float* out = (float*)d_out;

    const int nstrips = NMAPS * NSTRIP;   // 4096
    float* sval = (float*)d_ws;
    int*   sidx = (int*)((char*)d_ws + (size_t)nstrips * 4);
    int*   scnt = (int*)((char*)d_ws + (size_t)nstrips * 8);

    blur_peak_strip<<<nstrips / 4, 256, 0, stream>>>(in, sval, sidx, scnt);
    finalize_kernel<<<(NMAPS + 255) / 256, 256, 0, stream>>>(in, sval, sidx, scnt, out);
}